// Round 5
// baseline (1181.789 us; speedup 1.0000x reference)
//
#include <hip/hip_runtime.h>

typedef __attribute__((ext_vector_type(4))) float f32x4;
typedef __attribute__((ext_vector_type(8))) short short8;
typedef __attribute__((ext_vector_type(8))) _Float16 half8;
typedef __attribute__((ext_vector_type(4))) _Float16 half4;

__device__ inline f32x4 mfma_fp16(half8 a, half8 b, f32x4 c) {
  return __builtin_amdgcn_mfma_f32_16x16x32_f16(a, b, c, 0, 0, 0);
}

// XOR-swizzled element index for [64 rows][64 cols] fp16 tile (row stride 128B).
// byte = row*128 + colbyte, swizzled byte ^= (row&7)<<4; all offsets 16B-aligned.
__device__ inline int kva(int row, int colbyte) {
  return ((row * 128 + colbyte) ^ ((row & 7) << 4)) >> 1;
}

// W (K x N) fp32 row-major -> transposed fp16 hi/lo planes (N x K), lo scaled x1024
__global__ __launch_bounds__(256) void wsplit_kernel(const float* __restrict__ W,
                                                     _Float16* __restrict__ Whi,
                                                     _Float16* __restrict__ Wlo) {
  int i = blockIdx.x * 256 + threadIdx.x;
  int k = i / 768, n = i % 768;
  float w = W[i];
  _Float16 h = (_Float16)w;
  Whi[n * 768 + k] = h;
  Wlo[n * 768 + k] = (_Float16)((w - (float)h) * 1024.0f);
}

// Vt plane base (in elements) for (b, head). Per-b size = 3,670,016 elems.
__device__ inline int vt_base(int b, int h) {
  int base = b * 3670016;
  if (h < 4)      base += h * 524288;
  else if (h < 8) base += 2097152 + (h - 4) * 262144;
  else            base += 3145728 + (h - 8) * 131072;
  return base;
}

// High-precision GEMM via fp16-pair split: C = A(fp32 MxK) @ Wt^T + bias.
// mode 0: fp16 hi/lo row-major out (Q,K)   mode 1: V compact-transposed hi/lo out
__global__ __launch_bounds__(256) void gemm3_kernel(
    const float* __restrict__ A, const _Float16* __restrict__ Bhi,
    const _Float16* __restrict__ Blo, const float* __restrict__ bias,
    _Float16* __restrict__ Chi, _Float16* __restrict__ Clo, int mode) {
  const int K = 768;
  __shared__ _Float16 Ah[128 * 72], Al[128 * 72];
  __shared__ _Float16 Bh[128 * 72], Bl[128 * 72];
  int tid = threadIdx.x;
  int m0 = blockIdx.y * 128, n0 = blockIdx.x * 128;
  int lane = tid & 63, wid = tid >> 6;
  int wm = wid >> 1, wn = wid & 1;
  int lg = lane >> 4, lc = lane & 15;

  f32x4 acch[4][4] = {};
  f32x4 accl[4][4] = {};

  for (int k0 = 0; k0 < K; k0 += 64) {
    __syncthreads();
#pragma unroll
    for (int c = 0; c < 4; ++c) {
      int idx = c * 256 + tid;
      int m = idx >> 3, kk = (idx & 7) << 3;
      const float* src = A + (size_t)(m0 + m) * K + k0 + kk;
      f32x4 x0 = *(const f32x4*)src;
      f32x4 x1 = *(const f32x4*)(src + 4);
      half8 vh, vl;
#pragma unroll
      for (int j = 0; j < 4; ++j) {
        _Float16 h0 = (_Float16)x0[j];
        vh[j] = h0; vl[j] = (_Float16)((x0[j] - (float)h0) * 1024.0f);
        _Float16 h1 = (_Float16)x1[j];
        vh[4 + j] = h1; vl[4 + j] = (_Float16)((x1[j] - (float)h1) * 1024.0f);
      }
      *(half8*)(&Ah[m * 72 + kk]) = vh;
      *(half8*)(&Al[m * 72 + kk]) = vl;
      *(half8*)(&Bh[m * 72 + kk]) = *(const half8*)(Bhi + (size_t)(n0 + m) * K + k0 + kk);
      *(half8*)(&Bl[m * 72 + kk]) = *(const half8*)(Blo + (size_t)(n0 + m) * K + k0 + kk);
    }
    __syncthreads();
#pragma unroll
    for (int ks = 0; ks < 2; ++ks) {
      half8 ah[4], al[4], bh[4], bl[4];
#pragma unroll
      for (int mt = 0; mt < 4; ++mt) {
        int ro = (wm * 64 + mt * 16 + lc) * 72 + ks * 32 + (lg << 3);
        ah[mt] = *(half8*)(&Ah[ro]);
        al[mt] = *(half8*)(&Al[ro]);
      }
#pragma unroll
      for (int nf = 0; nf < 4; ++nf) {
        int ro = (wn * 64 + nf * 16 + lc) * 72 + ks * 32 + (lg << 3);
        bh[nf] = *(half8*)(&Bh[ro]);
        bl[nf] = *(half8*)(&Bl[ro]);
      }
#pragma unroll
      for (int mt = 0; mt < 4; ++mt)
#pragma unroll
        for (int nf = 0; nf < 4; ++nf) {
          accl[mt][nf] = mfma_fp16(al[mt], bh[nf], accl[mt][nf]);
          accl[mt][nf] = mfma_fp16(ah[mt], bl[nf], accl[mt][nf]);
          acch[mt][nf] = mfma_fp16(ah[mt], bh[nf], acch[mt][nf]);
        }
    }
  }

#pragma unroll
  for (int mt = 0; mt < 4; ++mt)
#pragma unroll
    for (int nf = 0; nf < 4; ++nf) {
      int col = n0 + wn * 64 + nf * 16 + lc;
      int row0 = m0 + wm * 64 + mt * 16 + (lg << 2);
      float bv = bias[col];
#pragma unroll
      for (int rr = 0; rr < 4; ++rr) {
        int row = row0 + rr;
        float v = acch[mt][nf][rr] + accl[mt][nf][rr] * (1.0f / 1024.0f) + bv;
        _Float16 h = (_Float16)v;
        _Float16 l = (_Float16)((v - (float)h) * 1024.0f);
        if (mode == 0) {
          Chi[(size_t)row * 768 + col] = h;
          Clo[(size_t)row * 768 + col] = l;
        } else {
          int b = row >> 13, pos = row & 8191;
          int hh = col >> 6, d = col & 63;
          int g = hh >> 2;
          int rdil = 1 << g;
          if ((pos & (rdil - 1)) == g) {
            int t = (pos - g) >> g;
            int Ng = 8192 >> g;
            Chi[vt_base(b, hh) + d * Ng + t] = h;
            Clo[vt_base(b, hh) + d * Ng + t] = l;
          }
        }
      }
    }
}

// Single fp16 GEMM for output projection: C(fp32) = A(fp32) @ Wt^T + bias
__global__ __launch_bounds__(256) void gemm1_kernel(
    const float* __restrict__ A, const _Float16* __restrict__ Bt,
    const float* __restrict__ bias, float* __restrict__ C) {
  const int K = 768, N = 768;
  __shared__ _Float16 As[128 * 72];
  __shared__ _Float16 Bs[128 * 72];
  int tid = threadIdx.x;
  int m0 = blockIdx.y * 128, n0 = blockIdx.x * 128;
  int lane = tid & 63, wid = tid >> 6;
  int wm = wid >> 1, wn = wid & 1;
  int lg = lane >> 4, lc = lane & 15;

  f32x4 acc[4][4] = {};

  for (int k0 = 0; k0 < K; k0 += 64) {
    __syncthreads();
#pragma unroll
    for (int c = 0; c < 4; ++c) {
      int idx = c * 256 + tid;
      int m = idx >> 3, kk = (idx & 7) << 3;
      const float* src = A + (size_t)(m0 + m) * K + k0 + kk;
      f32x4 x0 = *(const f32x4*)src;
      f32x4 x1 = *(const f32x4*)(src + 4);
      half8 v;
#pragma unroll
      for (int j = 0; j < 4; ++j) { v[j] = (_Float16)x0[j]; v[4 + j] = (_Float16)x1[j]; }
      *(half8*)(&As[m * 72 + kk]) = v;
      *(half8*)(&Bs[m * 72 + kk]) = *(const half8*)(Bt + (size_t)(n0 + m) * K + k0 + kk);
    }
    __syncthreads();
#pragma unroll
    for (int ks = 0; ks < 2; ++ks) {
      half8 af[4], bf[4];
#pragma unroll
      for (int mt = 0; mt < 4; ++mt)
        af[mt] = *(half8*)(&As[(wm * 64 + mt * 16 + lc) * 72 + ks * 32 + (lg << 3)]);
#pragma unroll
      for (int nf = 0; nf < 4; ++nf)
        bf[nf] = *(half8*)(&Bs[(wn * 64 + nf * 16 + lc) * 72 + ks * 32 + (lg << 3)]);
#pragma unroll
      for (int mt = 0; mt < 4; ++mt)
#pragma unroll
        for (int nf = 0; nf < 4; ++nf)
          acc[mt][nf] = mfma_fp16(af[mt], bf[nf], acc[mt][nf]);
    }
  }

#pragma unroll
  for (int mt = 0; mt < 4; ++mt)
#pragma unroll
    for (int nf = 0; nf < 4; ++nf) {
      int col = n0 + wn * 64 + nf * 16 + lc;
      int row0 = m0 + wm * 64 + mt * 16 + (lg << 2);
      float bv = bias[col];
#pragma unroll
      for (int rr = 0; rr < 4; ++rr)
        C[(size_t)(row0 + rr) * N + col] = acc[mt][nf][rr] + bv;
    }
}

// Two-pass dilated flash attention, fp16-pair precision.
// 512 threads (8 waves), 128 q-rows/block, XCD-swizzled, 52.2KB LDS (3 blocks/CU).
__global__ __launch_bounds__(512, 6) void attn_kernel(
    const _Float16* __restrict__ Qh, const _Float16* __restrict__ Ql,
    const _Float16* __restrict__ Kh, const _Float16* __restrict__ Kl,
    const _Float16* __restrict__ Vth, const _Float16* __restrict__ Vtl,
    float* __restrict__ X, float* __restrict__ wbuf) {
  __shared__ _Float16 Ksh[64 * 64], Ksl[64 * 64];   // XOR-swizzled, stride 64
  __shared__ _Float16 Vsh[64 * 64], Vsl[64 * 64];
  __shared__ _Float16 Ps[8 * 16 * 68];              // P: stride 68 (conflict-free writes)
  __shared__ float colred[8][64];

  // XCD-aware decode: pin each unit's 16 q-blocks to one XCD (K/V L2 reuse).
  int bid = blockIdx.x;
  int xcd = bid & 7, idx = bid >> 3;          // 112 slots/XCD = 7 units x 16 qblk
  int u_glob = xcd * 7 + (idx >> 4);          // 0..55
  int qblk = idx & 15;
  int g = (u_glob < 32) ? 0 : (u_glob < 48) ? 1 : 2;
  int u = (g == 0) ? u_glob : (g == 1) ? u_glob - 32 : u_glob - 48;
  int nsegs = 4 >> g;
  int b = u / (nsegs * 4), rem = u % (nsegs * 4);
  int nseg = rem >> 2, hg = rem & 3;
  int head = g * 4 + hg;
  int s = 2048 << g, r = 1 << g, off = g;
  int Ng = 8192 >> g;
  int tbase = nseg * 2048;
  int vbase = vt_base(b, head);

  int tid = threadIdx.x, lane = tid & 63, wid = tid >> 6;
  int lg = lane >> 4, lc = lane & 15;

  int q0 = qblk * 128 + wid * 16;
  half8 qfh[2], qfl[2];
  {
    int q = q0 + lc;
    int pos = nseg * s + off + q * r;
    size_t ro = (size_t)(b * 8192 + pos) * 768 + head * 64;
#pragma unroll
    for (int ks = 0; ks < 2; ++ks) {
      qfh[ks] = *(const half8*)(Qh + ro + ks * 32 + (lg << 3));
      qfl[ks] = *(const half8*)(Ql + ro + ks * 32 + (lg << 3));
    }
  }

  // Hoisted staging addresses (stride over kt is constant).
  int kr = tid >> 3, kcb = (tid & 7) << 4;  // row, col-bytes (16B per thread)
  const int kc = (tid & 7) << 3;            // col elems
  size_t kro = (size_t)(b * 8192 + nseg * s + off + kr * r) * 768 + head * 64 + kc;
  size_t vro = (size_t)vbase + (size_t)kr * Ng + tbase + kc;
  const size_t kstep = (size_t)64 * r * 768;
  _Float16* KshW = &Ksh[kva(kr, kcb)];
  _Float16* KslW = &Ksl[kva(kr, kcb)];
  _Float16* VshW = &Vsh[kva(kr, kcb)];
  _Float16* VslW = &Vsl[kva(kr, kcb)];

  // ---------- pass 1: cheap row sums (hi-only scores) ----------
  float psum[4] = {};
  {
    size_t kro1 = kro;
    for (int kt = 0; kt < 32; ++kt) {
      __syncthreads();
      *(half8*)KshW = *(const half8*)(Kh + kro1);
      kro1 += kstep;
      __syncthreads();
      f32x4 sc[4] = {};
#pragma unroll
      for (int ks = 0; ks < 2; ++ks)
#pragma unroll
        for (int nf = 0; nf < 4; ++nf) {
          half8 bf = *(half8*)(&Ksh[kva(nf * 16 + lc, ks * 64 + (lg << 4))]);
          sc[nf] = mfma_fp16(qfh[ks], bf, sc[nf]);
        }
#pragma unroll
      for (int rr = 0; rr < 4; ++rr) {
        float acc = 0.f;
#pragma unroll
        for (int nf = 0; nf < 4; ++nf) acc += __expf(sc[nf][rr] * 0.125f);
        psum[rr] += acc;
      }
    }
  }
  float inv_l[4];
#pragma unroll
  for (int rr = 0; rr < 4; ++rr) {
    float v = psum[rr];
#pragma unroll
    for (int msk = 1; msk < 16; msk <<= 1) v += __shfl_xor(v, msk, 64);
    inv_l[rr] = 1.0f / v;
  }

  // ---------- pass 2: precise scores, PV, column sums ----------
  f32x4 acch[4] = {};
  f32x4 accl[4] = {};
  _Float16* Pw = Ps + wid * 16 * 68;
  int wrow = ((b * 12 + head) * 16 + qblk) * 8192 + tbase;

  for (int kt = 0; kt < 32; ++kt) {
    int kv0 = kt * 64;
    __syncthreads();
    // flush previous tile's column sums (colred complete as of the barrier)
    if (kt > 0 && tid < 64) {
      float w4 = 0.f;
#pragma unroll
      for (int w = 0; w < 8; ++w) w4 += colred[w][tid];
      wbuf[wrow + (kv0 - 64) + tid] = w4;
    }
    *(half8*)KshW = *(const half8*)(Kh + kro);
    *(half8*)KslW = *(const half8*)(Kl + kro);
    *(half8*)VshW = *(const half8*)(Vth + vro);
    *(half8*)VslW = *(const half8*)(Vtl + vro);
    kro += kstep;
    vro += 64;
    __syncthreads();

    // precise scores: s = hi*hi + (hi*lo + lo*hi)/1024
    f32x4 sc[4];
#pragma unroll
    for (int nf = 0; nf < 4; ++nf) {
      half8 kh[2], kl[2];
#pragma unroll
      for (int ks = 0; ks < 2; ++ks) {
        int ro = kva(nf * 16 + lc, ks * 64 + (lg << 4));
        kh[ks] = *(half8*)(&Ksh[ro]);
        kl[ks] = *(half8*)(&Ksl[ro]);
      }
      f32x4 t = {};
#pragma unroll
      for (int ks = 0; ks < 2; ++ks) {
        t = mfma_fp16(qfl[ks], kh[ks], t);
        t = mfma_fp16(qfh[ks], kl[ks], t);
      }
#pragma unroll
      for (int rr = 0; rr < 4; ++rr) t[rr] *= (1.0f / 1024.0f);
#pragma unroll
      for (int ks = 0; ks < 2; ++ks)
        t = mfma_fp16(qfh[ks], kh[ks], t);
      sc[nf] = t;
    }

    // p = e^{s/8} / l, rounded to fp16; column sums use the ROUNDED p
#pragma unroll
    for (int nf = 0; nf < 4; ++nf)
#pragma unroll
      for (int rr = 0; rr < 4; ++rr) {
        float p = __expf(sc[nf][rr] * 0.125f) * inv_l[rr];
        sc[nf][rr] = (float)(_Float16)p;
      }

#pragma unroll
    for (int nf = 0; nf < 4; ++nf) {
      float cs = sc[nf][0] + sc[nf][1] + sc[nf][2] + sc[nf][3];
      cs += __shfl_xor(cs, 16, 64);
      cs += __shfl_xor(cs, 32, 64);
      if (lane < 16) colred[wid][nf * 16 + lc] = cs;
    }

    // P -> per-wave LDS (D-layout -> A-layout), stride 68
#pragma unroll
    for (int nf = 0; nf < 4; ++nf)
#pragma unroll
      for (int rr = 0; rr < 4; ++rr)
        Pw[((lg << 2) + rr) * 68 + nf * 16 + lc] = (_Float16)sc[nf][rr];

    // PV: x = sum p*(vh + vl/1024)   (per-wave P buffer: no barrier needed)
#pragma unroll
    for (int ks2 = 0; ks2 < 2; ++ks2) {
      half4 plo = *(half4*)(&Pw[lc * 68 + ks2 * 32 + (lg << 3)]);
      half4 phi = *(half4*)(&Pw[lc * 68 + ks2 * 32 + (lg << 3) + 4]);
      half8 pa;
#pragma unroll
      for (int j = 0; j < 4; ++j) { pa[j] = plo[j]; pa[4 + j] = phi[j]; }
#pragma unroll
      for (int nf = 0; nf < 4; ++nf) {
        int ro = kva(nf * 16 + lc, ks2 * 64 + (lg << 4));
        half8 vh = *(half8*)(&Vsh[ro]);
        half8 vl = *(half8*)(&Vsl[ro]);
        acch[nf] = mfma_fp16(pa, vh, acch[nf]);
        accl[nf] = mfma_fp16(pa, vl, accl[nf]);
      }
    }
  }
  __syncthreads();
  if (tid < 64) {
    float w4 = 0.f;
#pragma unroll
    for (int w = 0; w < 8; ++w) w4 += colred[w][tid];
    wbuf[wrow + 31 * 64 + tid] = w4;
  }

  // epilogue
#pragma unroll
  for (int rr = 0; rr < 4; ++rr) {
    int q = q0 + (lg << 2) + rr;
    int pos = nseg * s + off + q * r;
    float* xr = X + (size_t)(b * 8192 + pos) * 768 + head * 64;
#pragma unroll
    for (int nf = 0; nf < 4; ++nf)
      xr[nf * 16 + lc] = acch[nf][rr] + accl[nf][rr] * (1.0f / 1024.0f);
  }
}

// wtot[b,h,t] = sum over 16 qblk partials
__global__ __launch_bounds__(256) void wreduce_kernel(const float* __restrict__ wbuf,
                                                      float* __restrict__ wtot) {
  int bh = blockIdx.y;
  int t = blockIdx.x * 256 + threadIdx.x;
  int h = bh % 12, g = h >> 2, Ng = 8192 >> g;
  if (t >= Ng) return;
  const float* src = wbuf + (size_t)bh * 16 * 8192 + t;
  float sacc = 0.f;
#pragma unroll
  for (int qb = 0; qb < 16; ++qb) sacc += src[qb * 8192];
  wtot[bh * 8192 + t] = sacc;
}

// div[b,h,d] = sum_t wtot[b,h,t] * (vh + vl/1024)  — consistent with PV's V
__global__ __launch_bounds__(256) void divgemm_kernel(const float* __restrict__ wtot,
                                                      const _Float16* __restrict__ Vth,
                                                      const _Float16* __restrict__ Vtl,
                                                      float* __restrict__ divbuf) {
  int bhd = blockIdx.x;  // 0..1535
  int b = bhd / 768, e = bhd % 768;
  int h = e >> 6, d = e & 63;
  int g = h >> 2, Ng = 8192 >> g;
  const _Float16* vph = Vth + vt_base(b, h) + d * Ng;
  const _Float16* vpl = Vtl + vt_base(b, h) + d * Ng;
  const float* wp = wtot + (b * 12 + h) * 8192;
  int tid = threadIdx.x;
  float sacc = 0.f;
  for (int t = tid; t < Ng; t += 256) {
    float v = (float)vph[t] + (float)vpl[t] * (1.0f / 1024.0f);
    sacc += wp[t] * v;
  }
  __shared__ float red[256];
  red[tid] = sacc;
  __syncthreads();
  for (int o = 128; o > 0; o >>= 1) {
    if (tid < o) red[tid] += red[tid + o];
    __syncthreads();
  }
  if (tid == 0) divbuf[b * 768 + e] = red[0];
}

// LayerNorm fusing the /(div*3) normalization + written-slot mask. In-place on X.
__global__ __launch_bounds__(256) void ln_kernel(float* __restrict__ X,
                                                 const float* __restrict__ divbuf,
                                                 const float* __restrict__ ln_w,
                                                 const float* __restrict__ ln_b) {
  int row = blockIdx.x;
  int b = row >> 13, pos = row & 8191;
  int tid = threadIdx.x;
  float x[3];
#pragma unroll
  for (int j = 0; j < 3; ++j) {
    int e = tid + 256 * j;
    int h = e >> 6, g = h >> 2;
    bool wr = (g == 0) || (g == 1 && (pos & 1) == 1) || (g == 2 && (pos & 3) == 2);
    float v = 0.f;
    if (wr) v = X[(size_t)row * 768 + e] / (divbuf[b * 768 + e] * 3.0f);
    x[j] = v;
  }
  float s1 = x[0] + x[1] + x[2];
  float s2 = x[0] * x[0] + x[1] * x[1] + x[2] * x[2];
  __shared__ float red[512];
  red[tid] = s1;
  red[256 + tid] = s2;
  __syncthreads();
  for (int o = 128; o > 0; o >>= 1) {
    if (tid < o) {
      red[tid] += red[tid + o];
      red[256 + tid] += red[256 + tid + o];
    }
    __syncthreads();
  }
  float mean = red[0] * (1.0f / 768.0f);
  float var = red[256] * (1.0f / 768.0f) - mean * mean;
  float inv = rsqrtf(var + 1e-5f);
#pragma unroll
  for (int j = 0; j < 3; ++j) {
    int e = tid + 256 * j;
    X[(size_t)row * 768 + e] = (x[j] - mean) * inv * ln_w[e] + ln_b[e];
  }
}

extern "C" void kernel_launch(void* const* d_in, const int* in_sizes, int n_in,
                              void* d_out, int out_size, void* d_ws, size_t ws_size,
                              hipStream_t stream) {
  const float* query = (const float*)d_in[0];
  const float* key   = (const float*)d_in[1];
  const float* value = (const float*)d_in[2];
  const float* Wq = (const float*)d_in[3];
  const float* bq = (const float*)d_in[4];
  const float* Wk = (const float*)d_in[5];
  const float* bk = (const float*)d_in[6];
  const float* Wv = (const float*)d_in[7];
  const float* bv = (const float*)d_in[8];
  const float* Wo = (const float*)d_in[9];
  const float* bo = (const float*)d_in[10];
  const float* ln_w = (const float*)d_in[11];
  const float* ln_b = (const float*)d_in[12];

  char* ws = (char*)d_ws;
  _Float16* Wqh = (_Float16*)ws; ws += 768 * 768 * 2;
  _Float16* Wql = (_Float16*)ws; ws += 768 * 768 * 2;
  _Float16* Wkh = (_Float16*)ws; ws += 768 * 768 * 2;
  _Float16* Wkl = (_Float16*)ws; ws += 768 * 768 * 2;
  _Float16* Wvh = (_Float16*)ws; ws += 768 * 768 * 2;
  _Float16* Wvl = (_Float16*)ws; ws += 768 * 768 * 2;
  _Float16* Woh = (_Float16*)ws; ws += 768 * 768 * 2;
  _Float16* Wol = (_Float16*)ws; ws += 768 * 768 * 2;
  _Float16* Qhb = (_Float16*)ws; ws += (size_t)16384 * 768 * 2;
  _Float16* Qlb = (_Float16*)ws; ws += (size_t)16384 * 768 * 2;
  _Float16* Khb = (_Float16*)ws; ws += (size_t)16384 * 768 * 2;
  _Float16* Klb = (_Float16*)ws; ws += (size_t)16384 * 768 * 2;
  _Float16* Vth = (_Float16*)ws; ws += (size_t)7340032 * 2;
  _Float16* Vtl = (_Float16*)ws; ws += (size_t)7340032 * 2;
  float* Xbuf = (float*)ws; ws += (size_t)16384 * 768 * 4;
  float* wbuf = (float*)ws; ws += (size_t)24 * 16 * 8192 * 4;
  float* wtot = (float*)ws; ws += (size_t)24 * 8192 * 4;
  float* divbuf = (float*)ws; ws += 2 * 768 * 4;

  wsplit_kernel<<<2304, 256, 0, stream>>>(Wq, Wqh, Wql);
  wsplit_kernel<<<2304, 256, 0, stream>>>(Wk, Wkh, Wkl);
  wsplit_kernel<<<2304, 256, 0, stream>>>(Wv, Wvh, Wvl);
  wsplit_kernel<<<2304, 256, 0, stream>>>(Wo, Woh, Wol);

  dim3 ggrid(6, 128);
  gemm3_kernel<<<ggrid, 256, 0, stream>>>(query, Wqh, Wql, bq, Qhb, Qlb, 0);
  gemm3_kernel<<<ggrid, 256, 0, stream>>>(key,   Wkh, Wkl, bk, Khb, Klb, 0);
  gemm3_kernel<<<ggrid, 256, 0, stream>>>(value, Wvh, Wvl, bv, Vth, Vtl, 1);

  attn_kernel<<<896, 512, 0, stream>>>(Qhb, Qlb, Khb, Klb, Vth, Vtl, Xbuf, wbuf);

  wreduce_kernel<<<dim3(32, 24), 256, 0, stream>>>(wbuf, wtot);
  divgemm_kernel<<<1536, 256, 0, stream>>>(wtot, Vth, Vtl, divbuf);
  ln_kernel<<<16384, 256, 0, stream>>>(Xbuf, divbuf, ln_w, ln_b);

  gemm1_kernel<<<ggrid, 256, 0, stream>>>(Xbuf, Woh, bo, (float*)d_out);
}

// Round 6
// 849.349 us; speedup vs baseline: 1.3914x; 1.3914x over previous
//
#include <hip/hip_runtime.h>

typedef __attribute__((ext_vector_type(4))) float f32x4;
typedef __attribute__((ext_vector_type(8))) short short8;
typedef __attribute__((ext_vector_type(8))) _Float16 half8;
typedef __attribute__((ext_vector_type(4))) _Float16 half4;

__device__ inline f32x4 mfma_fp16(half8 a, half8 b, f32x4 c) {
  return __builtin_amdgcn_mfma_f32_16x16x32_f16(a, b, c, 0, 0, 0);
}

// XOR-swizzled element index for [64 rows][64 cols] fp16 tile (row stride 128B).
// byte = row*128 + colbyte, swizzled byte ^= (row&7)<<4; all offsets 16B-aligned.
__device__ inline int kva(int row, int colbyte) {
  return ((row * 128 + colbyte) ^ ((row & 7) << 4)) >> 1;
}

// W (K x N) fp32 row-major -> transposed fp16 hi/lo planes (N x K), lo scaled x1024
__global__ __launch_bounds__(256) void wsplit_kernel(const float* __restrict__ W,
                                                     _Float16* __restrict__ Whi,
                                                     _Float16* __restrict__ Wlo) {
  int i = blockIdx.x * 256 + threadIdx.x;
  int k = i / 768, n = i % 768;
  float w = W[i];
  _Float16 h = (_Float16)w;
  Whi[n * 768 + k] = h;
  Wlo[n * 768 + k] = (_Float16)((w - (float)h) * 1024.0f);
}

// Vt plane base (in elements) for (b, head). Per-b size = 3,670,016 elems.
__device__ inline int vt_base(int b, int h) {
  int base = b * 3670016;
  if (h < 4)      base += h * 524288;
  else if (h < 8) base += 2097152 + (h - 4) * 262144;
  else            base += 3145728 + (h - 8) * 131072;
  return base;
}

// High-precision GEMM via fp16-pair split: C = A(fp32 MxK) @ Wt^T + bias.
// mode 0: fp16 hi/lo row-major out (Q,K)   mode 1: V compact-transposed hi/lo out
__global__ __launch_bounds__(256) void gemm3_kernel(
    const float* __restrict__ A, const _Float16* __restrict__ Bhi,
    const _Float16* __restrict__ Blo, const float* __restrict__ bias,
    _Float16* __restrict__ Chi, _Float16* __restrict__ Clo, int mode) {
  const int K = 768;
  __shared__ _Float16 Ah[128 * 72], Al[128 * 72];
  __shared__ _Float16 Bh[128 * 72], Bl[128 * 72];
  int tid = threadIdx.x;
  int m0 = blockIdx.y * 128, n0 = blockIdx.x * 128;
  int lane = tid & 63, wid = tid >> 6;
  int wm = wid >> 1, wn = wid & 1;
  int lg = lane >> 4, lc = lane & 15;

  f32x4 acch[4][4] = {};
  f32x4 accl[4][4] = {};

  for (int k0 = 0; k0 < K; k0 += 64) {
    __syncthreads();
#pragma unroll
    for (int c = 0; c < 4; ++c) {
      int idx = c * 256 + tid;
      int m = idx >> 3, kk = (idx & 7) << 3;
      const float* src = A + (size_t)(m0 + m) * K + k0 + kk;
      f32x4 x0 = *(const f32x4*)src;
      f32x4 x1 = *(const f32x4*)(src + 4);
      half8 vh, vl;
#pragma unroll
      for (int j = 0; j < 4; ++j) {
        _Float16 h0 = (_Float16)x0[j];
        vh[j] = h0; vl[j] = (_Float16)((x0[j] - (float)h0) * 1024.0f);
        _Float16 h1 = (_Float16)x1[j];
        vh[4 + j] = h1; vl[4 + j] = (_Float16)((x1[j] - (float)h1) * 1024.0f);
      }
      *(half8*)(&Ah[m * 72 + kk]) = vh;
      *(half8*)(&Al[m * 72 + kk]) = vl;
      *(half8*)(&Bh[m * 72 + kk]) = *(const half8*)(Bhi + (size_t)(n0 + m) * K + k0 + kk);
      *(half8*)(&Bl[m * 72 + kk]) = *(const half8*)(Blo + (size_t)(n0 + m) * K + k0 + kk);
    }
    __syncthreads();
#pragma unroll
    for (int ks = 0; ks < 2; ++ks) {
      half8 ah[4], al[4], bh[4], bl[4];
#pragma unroll
      for (int mt = 0; mt < 4; ++mt) {
        int ro = (wm * 64 + mt * 16 + lc) * 72 + ks * 32 + (lg << 3);
        ah[mt] = *(half8*)(&Ah[ro]);
        al[mt] = *(half8*)(&Al[ro]);
      }
#pragma unroll
      for (int nf = 0; nf < 4; ++nf) {
        int ro = (wn * 64 + nf * 16 + lc) * 72 + ks * 32 + (lg << 3);
        bh[nf] = *(half8*)(&Bh[ro]);
        bl[nf] = *(half8*)(&Bl[ro]);
      }
#pragma unroll
      for (int mt = 0; mt < 4; ++mt)
#pragma unroll
        for (int nf = 0; nf < 4; ++nf) {
          accl[mt][nf] = mfma_fp16(al[mt], bh[nf], accl[mt][nf]);
          accl[mt][nf] = mfma_fp16(ah[mt], bl[nf], accl[mt][nf]);
          acch[mt][nf] = mfma_fp16(ah[mt], bh[nf], acch[mt][nf]);
        }
    }
  }

#pragma unroll
  for (int mt = 0; mt < 4; ++mt)
#pragma unroll
    for (int nf = 0; nf < 4; ++nf) {
      int col = n0 + wn * 64 + nf * 16 + lc;
      int row0 = m0 + wm * 64 + mt * 16 + (lg << 2);
      float bv = bias[col];
#pragma unroll
      for (int rr = 0; rr < 4; ++rr) {
        int row = row0 + rr;
        float v = acch[mt][nf][rr] + accl[mt][nf][rr] * (1.0f / 1024.0f) + bv;
        _Float16 h = (_Float16)v;
        _Float16 l = (_Float16)((v - (float)h) * 1024.0f);
        if (mode == 0) {
          Chi[(size_t)row * 768 + col] = h;
          Clo[(size_t)row * 768 + col] = l;
        } else {
          int b = row >> 13, pos = row & 8191;
          int hh = col >> 6, d = col & 63;
          int g = hh >> 2;
          int rdil = 1 << g;
          if ((pos & (rdil - 1)) == g) {
            int t = (pos - g) >> g;
            int Ng = 8192 >> g;
            Chi[vt_base(b, hh) + d * Ng + t] = h;
            Clo[vt_base(b, hh) + d * Ng + t] = l;
          }
        }
      }
    }
}

// Single fp16 GEMM for output projection: C(fp32) = A(fp32) @ Wt^T + bias
__global__ __launch_bounds__(256) void gemm1_kernel(
    const float* __restrict__ A, const _Float16* __restrict__ Bt,
    const float* __restrict__ bias, float* __restrict__ C) {
  const int K = 768, N = 768;
  __shared__ _Float16 As[128 * 72];
  __shared__ _Float16 Bs[128 * 72];
  int tid = threadIdx.x;
  int m0 = blockIdx.y * 128, n0 = blockIdx.x * 128;
  int lane = tid & 63, wid = tid >> 6;
  int wm = wid >> 1, wn = wid & 1;
  int lg = lane >> 4, lc = lane & 15;

  f32x4 acc[4][4] = {};

  for (int k0 = 0; k0 < K; k0 += 64) {
    __syncthreads();
#pragma unroll
    for (int c = 0; c < 4; ++c) {
      int idx = c * 256 + tid;
      int m = idx >> 3, kk = (idx & 7) << 3;
      const float* src = A + (size_t)(m0 + m) * K + k0 + kk;
      f32x4 x0 = *(const f32x4*)src;
      f32x4 x1 = *(const f32x4*)(src + 4);
      half8 v;
#pragma unroll
      for (int j = 0; j < 4; ++j) { v[j] = (_Float16)x0[j]; v[4 + j] = (_Float16)x1[j]; }
      *(half8*)(&As[m * 72 + kk]) = v;
      *(half8*)(&Bs[m * 72 + kk]) = *(const half8*)(Bt + (size_t)(n0 + m) * K + k0 + kk);
    }
    __syncthreads();
#pragma unroll
    for (int ks = 0; ks < 2; ++ks) {
      half8 af[4], bf[4];
#pragma unroll
      for (int mt = 0; mt < 4; ++mt)
        af[mt] = *(half8*)(&As[(wm * 64 + mt * 16 + lc) * 72 + ks * 32 + (lg << 3)]);
#pragma unroll
      for (int nf = 0; nf < 4; ++nf)
        bf[nf] = *(half8*)(&Bs[(wn * 64 + nf * 16 + lc) * 72 + ks * 32 + (lg << 3)]);
#pragma unroll
      for (int mt = 0; mt < 4; ++mt)
#pragma unroll
        for (int nf = 0; nf < 4; ++nf)
          acc[mt][nf] = mfma_fp16(af[mt], bf[nf], acc[mt][nf]);
    }
  }

#pragma unroll
  for (int mt = 0; mt < 4; ++mt)
#pragma unroll
    for (int nf = 0; nf < 4; ++nf) {
      int col = n0 + wn * 64 + nf * 16 + lc;
      int row0 = m0 + wm * 64 + mt * 16 + (lg << 2);
      float bv = bias[col];
#pragma unroll
      for (int rr = 0; rr < 4; ++rr)
        C[(size_t)(row0 + rr) * N + col] = acc[mt][nf][rr] + bv;
    }
}

// Two-pass dilated flash attention, fp16-pair precision.
// 512 threads (8 waves), 128 q-rows/block, XCD-swizzled, 52.2KB LDS.
// NOTE: 2nd launch_bounds arg behaves as BLOCKS/CU on this toolchain; 6 caused
// VGPR=40 + catastrophic scratch spills (R5). Keep 4 (VGPR=64, no spill).
__global__ __launch_bounds__(512, 4) void attn_kernel(
    const _Float16* __restrict__ Qh, const _Float16* __restrict__ Ql,
    const _Float16* __restrict__ Kh, const _Float16* __restrict__ Kl,
    const _Float16* __restrict__ Vth, const _Float16* __restrict__ Vtl,
    float* __restrict__ X, float* __restrict__ wbuf) {
  __shared__ _Float16 Ksh[64 * 64], Ksl[64 * 64];   // XOR-swizzled, stride 64
  __shared__ _Float16 Vsh[64 * 64], Vsl[64 * 64];
  __shared__ _Float16 Ps[8 * 16 * 68];              // P: stride 68 (conflict-free writes)
  __shared__ float colred[8][64];

  // XCD-aware decode: pin each unit's 16 q-blocks to one XCD (K/V L2 reuse).
  int bid = blockIdx.x;
  int xcd = bid & 7, idx = bid >> 3;          // 112 slots/XCD = 7 units x 16 qblk
  int u_glob = xcd * 7 + (idx >> 4);          // 0..55
  int qblk = idx & 15;
  int g = (u_glob < 32) ? 0 : (u_glob < 48) ? 1 : 2;
  int u = (g == 0) ? u_glob : (g == 1) ? u_glob - 32 : u_glob - 48;
  int nsegs = 4 >> g;
  int b = u / (nsegs * 4), rem = u % (nsegs * 4);
  int nseg = rem >> 2, hg = rem & 3;
  int head = g * 4 + hg;
  int s = 2048 << g, r = 1 << g, off = g;
  int Ng = 8192 >> g;
  int tbase = nseg * 2048;
  int vbase = vt_base(b, head);

  int tid = threadIdx.x, lane = tid & 63, wid = tid >> 6;
  int lg = lane >> 4, lc = lane & 15;

  int q0 = qblk * 128 + wid * 16;
  half8 qfh[2], qfl[2];
  {
    int q = q0 + lc;
    int pos = nseg * s + off + q * r;
    size_t ro = (size_t)(b * 8192 + pos) * 768 + head * 64;
#pragma unroll
    for (int ks = 0; ks < 2; ++ks) {
      qfh[ks] = *(const half8*)(Qh + ro + ks * 32 + (lg << 3));
      qfl[ks] = *(const half8*)(Ql + ro + ks * 32 + (lg << 3));
    }
  }

  // Hoisted staging addresses (stride over kt is constant).
  int kr = tid >> 3, kcb = (tid & 7) << 4;  // row, col-bytes (16B per thread)
  const int kc = (tid & 7) << 3;            // col elems
  size_t kro = (size_t)(b * 8192 + nseg * s + off + kr * r) * 768 + head * 64 + kc;
  size_t vro = (size_t)vbase + (size_t)kr * Ng + tbase + kc;
  const size_t kstep = (size_t)64 * r * 768;
  _Float16* KshW = &Ksh[kva(kr, kcb)];
  _Float16* KslW = &Ksl[kva(kr, kcb)];
  _Float16* VshW = &Vsh[kva(kr, kcb)];
  _Float16* VslW = &Vsl[kva(kr, kcb)];

  // ---------- pass 1: cheap row sums (hi-only scores) ----------
  float psum[4] = {};
  {
    size_t kro1 = kro;
    for (int kt = 0; kt < 32; ++kt) {
      __syncthreads();
      *(half8*)KshW = *(const half8*)(Kh + kro1);
      kro1 += kstep;
      __syncthreads();
      f32x4 sc[4] = {};
#pragma unroll
      for (int ks = 0; ks < 2; ++ks)
#pragma unroll
        for (int nf = 0; nf < 4; ++nf) {
          half8 bf = *(half8*)(&Ksh[kva(nf * 16 + lc, ks * 64 + (lg << 4))]);
          sc[nf] = mfma_fp16(qfh[ks], bf, sc[nf]);
        }
#pragma unroll
      for (int rr = 0; rr < 4; ++rr) {
        float acc = 0.f;
#pragma unroll
        for (int nf = 0; nf < 4; ++nf) acc += __expf(sc[nf][rr] * 0.125f);
        psum[rr] += acc;
      }
    }
  }
  float inv_l[4];
#pragma unroll
  for (int rr = 0; rr < 4; ++rr) {
    float v = psum[rr];
#pragma unroll
    for (int msk = 1; msk < 16; msk <<= 1) v += __shfl_xor(v, msk, 64);
    inv_l[rr] = 1.0f / v;
  }

  // ---------- pass 2: precise scores, PV, column sums ----------
  f32x4 acch[4] = {};
  f32x4 accl[4] = {};
  _Float16* Pw = Ps + wid * 16 * 68;
  int wrow = ((b * 12 + head) * 16 + qblk) * 8192 + tbase;

  for (int kt = 0; kt < 32; ++kt) {
    int kv0 = kt * 64;
    __syncthreads();
    // flush previous tile's column sums (colred complete as of the barrier)
    if (kt > 0 && tid < 64) {
      float w4 = 0.f;
#pragma unroll
      for (int w = 0; w < 8; ++w) w4 += colred[w][tid];
      wbuf[wrow + (kv0 - 64) + tid] = w4;
    }
    *(half8*)KshW = *(const half8*)(Kh + kro);
    *(half8*)KslW = *(const half8*)(Kl + kro);
    *(half8*)VshW = *(const half8*)(Vth + vro);
    *(half8*)VslW = *(const half8*)(Vtl + vro);
    kro += kstep;
    vro += 64;
    __syncthreads();

    // precise scores: s = hi*hi + (hi*lo + lo*hi)/1024
    f32x4 sc[4];
#pragma unroll
    for (int nf = 0; nf < 4; ++nf) {
      half8 kh[2], kl[2];
#pragma unroll
      for (int ks = 0; ks < 2; ++ks) {
        int ro = kva(nf * 16 + lc, ks * 64 + (lg << 4));
        kh[ks] = *(half8*)(&Ksh[ro]);
        kl[ks] = *(half8*)(&Ksl[ro]);
      }
      f32x4 t = {};
#pragma unroll
      for (int ks = 0; ks < 2; ++ks) {
        t = mfma_fp16(qfl[ks], kh[ks], t);
        t = mfma_fp16(qfh[ks], kl[ks], t);
      }
#pragma unroll
      for (int rr = 0; rr < 4; ++rr) t[rr] *= (1.0f / 1024.0f);
#pragma unroll
      for (int ks = 0; ks < 2; ++ks)
        t = mfma_fp16(qfh[ks], kh[ks], t);
      sc[nf] = t;
    }

    // p = e^{s/8} / l, rounded to fp16; column sums use the ROUNDED p
#pragma unroll
    for (int nf = 0; nf < 4; ++nf)
#pragma unroll
      for (int rr = 0; rr < 4; ++rr) {
        float p = __expf(sc[nf][rr] * 0.125f) * inv_l[rr];
        sc[nf][rr] = (float)(_Float16)p;
      }

#pragma unroll
    for (int nf = 0; nf < 4; ++nf) {
      float cs = sc[nf][0] + sc[nf][1] + sc[nf][2] + sc[nf][3];
      cs += __shfl_xor(cs, 16, 64);
      cs += __shfl_xor(cs, 32, 64);
      if (lane < 16) colred[wid][nf * 16 + lc] = cs;
    }

    // P -> per-wave LDS (D-layout -> A-layout), stride 68
#pragma unroll
    for (int nf = 0; nf < 4; ++nf)
#pragma unroll
      for (int rr = 0; rr < 4; ++rr)
        Pw[((lg << 2) + rr) * 68 + nf * 16 + lc] = (_Float16)sc[nf][rr];

    // PV: x = sum p*(vh + vl/1024)   (per-wave P buffer: no barrier needed)
#pragma unroll
    for (int ks2 = 0; ks2 < 2; ++ks2) {
      half4 plo = *(half4*)(&Pw[lc * 68 + ks2 * 32 + (lg << 3)]);
      half4 phi = *(half4*)(&Pw[lc * 68 + ks2 * 32 + (lg << 3) + 4]);
      half8 pa;
#pragma unroll
      for (int j = 0; j < 4; ++j) { pa[j] = plo[j]; pa[4 + j] = phi[j]; }
#pragma unroll
      for (int nf = 0; nf < 4; ++nf) {
        int ro = kva(nf * 16 + lc, ks2 * 64 + (lg << 4));
        half8 vh = *(half8*)(&Vsh[ro]);
        half8 vl = *(half8*)(&Vsl[ro]);
        acch[nf] = mfma_fp16(pa, vh, acch[nf]);
        accl[nf] = mfma_fp16(pa, vl, accl[nf]);
      }
    }
  }
  __syncthreads();
  if (tid < 64) {
    float w4 = 0.f;
#pragma unroll
    for (int w = 0; w < 8; ++w) w4 += colred[w][tid];
    wbuf[wrow + 31 * 64 + tid] = w4;
  }

  // epilogue
#pragma unroll
  for (int rr = 0; rr < 4; ++rr) {
    int q = q0 + (lg << 2) + rr;
    int pos = nseg * s + off + q * r;
    float* xr = X + (size_t)(b * 8192 + pos) * 768 + head * 64;
#pragma unroll
    for (int nf = 0; nf < 4; ++nf)
      xr[nf * 16 + lc] = acch[nf][rr] + accl[nf][rr] * (1.0f / 1024.0f);
  }
}

// wtot[b,h,t] = sum over 16 qblk partials
__global__ __launch_bounds__(256) void wreduce_kernel(const float* __restrict__ wbuf,
                                                      float* __restrict__ wtot) {
  int bh = blockIdx.y;
  int t = blockIdx.x * 256 + threadIdx.x;
  int h = bh % 12, g = h >> 2, Ng = 8192 >> g;
  if (t >= Ng) return;
  const float* src = wbuf + (size_t)bh * 16 * 8192 + t;
  float sacc = 0.f;
#pragma unroll
  for (int qb = 0; qb < 16; ++qb) sacc += src[qb * 8192];
  wtot[bh * 8192 + t] = sacc;
}

// div[b,h,d] = sum_t wtot[b,h,t] * (vh + vl/1024)  — consistent with PV's V
__global__ __launch_bounds__(256) void divgemm_kernel(const float* __restrict__ wtot,
                                                      const _Float16* __restrict__ Vth,
                                                      const _Float16* __restrict__ Vtl,
                                                      float* __restrict__ divbuf) {
  int bhd = blockIdx.x;  // 0..1535
  int b = bhd / 768, e = bhd % 768;
  int h = e >> 6, d = e & 63;
  int g = h >> 2, Ng = 8192 >> g;
  const _Float16* vph = Vth + vt_base(b, h) + d * Ng;
  const _Float16* vpl = Vtl + vt_base(b, h) + d * Ng;
  const float* wp = wtot + (b * 12 + h) * 8192;
  int tid = threadIdx.x;
  float sacc = 0.f;
  for (int t = tid; t < Ng; t += 256) {
    float v = (float)vph[t] + (float)vpl[t] * (1.0f / 1024.0f);
    sacc += wp[t] * v;
  }
  __shared__ float red[256];
  red[tid] = sacc;
  __syncthreads();
  for (int o = 128; o > 0; o >>= 1) {
    if (tid < o) red[tid] += red[tid + o];
    __syncthreads();
  }
  if (tid == 0) divbuf[b * 768 + e] = red[0];
}

// LayerNorm fusing the /(div*3) normalization + written-slot mask. In-place on X.
__global__ __launch_bounds__(256) void ln_kernel(float* __restrict__ X,
                                                 const float* __restrict__ divbuf,
                                                 const float* __restrict__ ln_w,
                                                 const float* __restrict__ ln_b) {
  int row = blockIdx.x;
  int b = row >> 13, pos = row & 8191;
  int tid = threadIdx.x;
  float x[3];
#pragma unroll
  for (int j = 0; j < 3; ++j) {
    int e = tid + 256 * j;
    int h = e >> 6, g = h >> 2;
    bool wr = (g == 0) || (g == 1 && (pos & 1) == 1) || (g == 2 && (pos & 3) == 2);
    float v = 0.f;
    if (wr) v = X[(size_t)row * 768 + e] / (divbuf[b * 768 + e] * 3.0f);
    x[j] = v;
  }
  float s1 = x[0] + x[1] + x[2];
  float s2 = x[0] * x[0] + x[1] * x[1] + x[2] * x[2];
  __shared__ float red[512];
  red[tid] = s1;
  red[256 + tid] = s2;
  __syncthreads();
  for (int o = 128; o > 0; o >>= 1) {
    if (tid < o) {
      red[tid] += red[tid + o];
      red[256 + tid] += red[256 + tid + o];
    }
    __syncthreads();
  }
  float mean = red[0] * (1.0f / 768.0f);
  float var = red[256] * (1.0f / 768.0f) - mean * mean;
  float inv = rsqrtf(var + 1e-5f);
#pragma unroll
  for (int j = 0; j < 3; ++j) {
    int e = tid + 256 * j;
    X[(size_t)row * 768 + e] = (x[j] - mean) * inv * ln_w[e] + ln_b[e];
  }
}

extern "C" void kernel_launch(void* const* d_in, const int* in_sizes, int n_in,
                              void* d_out, int out_size, void* d_ws, size_t ws_size,
                              hipStream_t stream) {
  const float* query = (const float*)d_in[0];
  const float* key   = (const float*)d_in[1];
  const float* value = (const float*)d_in[2];
  const float* Wq = (const float*)d_in[3];
  const float* bq = (const float*)d_in[4];
  const float* Wk = (const float*)d_in[5];
  const float* bk = (const float*)d_in[6];
  const float* Wv = (const float*)d_in[7];
  const float* bv = (const float*)d_in[8];
  const float* Wo = (const float*)d_in[9];
  const float* bo = (const float*)d_in[10];
  const float* ln_w = (const float*)d_in[11];
  const float* ln_b = (const float*)d_in[12];

  char* ws = (char*)d_ws;
  _Float16* Wqh = (_Float16*)ws; ws += 768 * 768 * 2;
  _Float16* Wql = (_Float16*)ws; ws += 768 * 768 * 2;
  _Float16* Wkh = (_Float16*)ws; ws += 768 * 768 * 2;
  _Float16* Wkl = (_Float16*)ws; ws += 768 * 768 * 2;
  _Float16* Wvh = (_Float16*)ws; ws += 768 * 768 * 2;
  _Float16* Wvl = (_Float16*)ws; ws += 768 * 768 * 2;
  _Float16* Woh = (_Float16*)ws; ws += 768 * 768 * 2;
  _Float16* Wol = (_Float16*)ws; ws += 768 * 768 * 2;
  _Float16* Qhb = (_Float16*)ws; ws += (size_t)16384 * 768 * 2;
  _Float16* Qlb = (_Float16*)ws; ws += (size_t)16384 * 768 * 2;
  _Float16* Khb = (_Float16*)ws; ws += (size_t)16384 * 768 * 2;
  _Float16* Klb = (_Float16*)ws; ws += (size_t)16384 * 768 * 2;
  _Float16* Vth = (_Float16*)ws; ws += (size_t)7340032 * 2;
  _Float16* Vtl = (_Float16*)ws; ws += (size_t)7340032 * 2;
  float* Xbuf = (float*)ws; ws += (size_t)16384 * 768 * 4;
  float* wbuf = (float*)ws; ws += (size_t)24 * 16 * 8192 * 4;
  float* wtot = (float*)ws; ws += (size_t)24 * 8192 * 4;
  float* divbuf = (float*)ws; ws += 2 * 768 * 4;

  wsplit_kernel<<<2304, 256, 0, stream>>>(Wq, Wqh, Wql);
  wsplit_kernel<<<2304, 256, 0, stream>>>(Wk, Wkh, Wkl);
  wsplit_kernel<<<2304, 256, 0, stream>>>(Wv, Wvh, Wvl);
  wsplit_kernel<<<2304, 256, 0, stream>>>(Wo, Woh, Wol);

  dim3 ggrid(6, 128);
  gemm3_kernel<<<ggrid, 256, 0, stream>>>(query, Wqh, Wql, bq, Qhb, Qlb, 0);
  gemm3_kernel<<<ggrid, 256, 0, stream>>>(key,   Wkh, Wkl, bk, Khb, Klb, 0);
  gemm3_kernel<<<ggrid, 256, 0, stream>>>(value, Wvh, Wvl, bv, Vth, Vtl, 1);

  attn_kernel<<<896, 512, 0, stream>>>(Qhb, Qlb, Khb, Klb, Vth, Vtl, Xbuf, wbuf);

  wreduce_kernel<<<dim3(32, 24), 256, 0, stream>>>(wbuf, wtot);
  divgemm_kernel<<<1536, 256, 0, stream>>>(wtot, Vth, Vtl, divbuf);
  ln_kernel<<<16384, 256, 0, stream>>>(Xbuf, divbuf, ln_w, ln_b);

  gemm1_kernel<<<ggrid, 256, 0, stream>>>(Xbuf, Woh, bo, (float*)d_out);
}

// Round 7
// 782.827 us; speedup vs baseline: 1.5096x; 1.0850x over previous
//
#include <hip/hip_runtime.h>

typedef __attribute__((ext_vector_type(4))) float f32x4;
typedef __attribute__((ext_vector_type(8))) short short8;
typedef __attribute__((ext_vector_type(8))) _Float16 half8;
typedef __attribute__((ext_vector_type(4))) _Float16 half4;

__device__ inline f32x4 mfma_fp16(half8 a, half8 b, f32x4 c) {
  return __builtin_amdgcn_mfma_f32_16x16x32_f16(a, b, c, 0, 0, 0);
}

// XOR-swizzled element index for [64 rows][64 cols] fp16 tile (row stride 128B).
__device__ inline int kva(int row, int colbyte) {
  return ((row * 128 + colbyte) ^ ((row & 7) << 4)) >> 1;
}

// All 4 weight matrices (K x N fp32) -> transposed fp16 hi/lo planes (N x K), lo x1024.
// blockIdx.y selects the matrix; planes are consecutive in Whi/Wlo.
__global__ __launch_bounds__(256) void wsplit4_kernel(
    const float* __restrict__ Wq, const float* __restrict__ Wk,
    const float* __restrict__ Wv, const float* __restrict__ Wo,
    _Float16* __restrict__ Whi, _Float16* __restrict__ Wlo) {
  int w = blockIdx.y;
  const float* W = (w == 0) ? Wq : (w == 1) ? Wk : (w == 2) ? Wv : Wo;
  int i = blockIdx.x * 256 + threadIdx.x;
  int k = i / 768, n = i % 768;
  float v = W[i];
  _Float16 h = (_Float16)v;
  Whi[w * 589824 + n * 768 + k] = h;
  Wlo[w * 589824 + n * 768 + k] = (_Float16)((v - (float)h) * 1024.0f);
}

// fp32 activations (16384 x 768) -> fp16 hi/lo planes, same layout, lo x1024.
__global__ __launch_bounds__(256) void asplit_kernel(const float* __restrict__ A,
                                                     _Float16* __restrict__ Ahi,
                                                     _Float16* __restrict__ Alo) {
  int i = (blockIdx.x * 256 + threadIdx.x) * 8;
  f32x4 x0 = *(const f32x4*)(A + i);
  f32x4 x1 = *(const f32x4*)(A + i + 4);
  half8 vh, vl;
#pragma unroll
  for (int j = 0; j < 4; ++j) {
    _Float16 h0 = (_Float16)x0[j];
    vh[j] = h0; vl[j] = (_Float16)((x0[j] - (float)h0) * 1024.0f);
    _Float16 h1 = (_Float16)x1[j];
    vh[4 + j] = h1; vl[4 + j] = (_Float16)((x1[j] - (float)h1) * 1024.0f);
  }
  *(half8*)(Ahi + i) = vh;
  *(half8*)(Alo + i) = vl;
}

// Vt plane base (in elements) for (b, head). Per-b size = 3,670,016 elems.
__device__ inline int vt_base(int b, int h) {
  int base = b * 3670016;
  if (h < 4)      base += h * 524288;
  else if (h < 8) base += 2097152 + (h - 4) * 262144;
  else            base += 3145728 + (h - 8) * 131072;
  return base;
}

// High-precision GEMM, fp16-pair split, PRE-SPLIT A planes (no cvt in staging).
// 512 threads, 8 waves as (wm 0..3, wn 0..1), wave tile 32x64.
// mode 0: fp16 hi/lo row-major out (Q,K)   mode 1: V compact-transposed hi/lo out
__global__ __launch_bounds__(512, 2) void gemm3_kernel(
    const _Float16* __restrict__ Ahi, const _Float16* __restrict__ Alo,
    const _Float16* __restrict__ Bhi, const _Float16* __restrict__ Blo,
    const float* __restrict__ bias,
    _Float16* __restrict__ Chi, _Float16* __restrict__ Clo, int mode) {
  const int K = 768;
  __shared__ _Float16 Ah[128 * 72], Al[128 * 72];
  __shared__ _Float16 Bh[128 * 72], Bl[128 * 72];
  int tid = threadIdx.x;
  int m0 = blockIdx.y * 128, n0 = blockIdx.x * 128;
  int lane = tid & 63, wid = tid >> 6;
  int wm = wid >> 1, wn = wid & 1;
  int lg = lane >> 4, lc = lane & 15;

  f32x4 acch[2][4] = {};
  f32x4 accl[2][4] = {};

  for (int k0 = 0; k0 < K; k0 += 64) {
    __syncthreads();
#pragma unroll
    for (int c = 0; c < 2; ++c) {
      int idx = c * 512 + tid;
      int m = idx >> 3, kk = (idx & 7) << 3;
      size_t ra = (size_t)(m0 + m) * K + k0 + kk;
      size_t rb = (size_t)(n0 + m) * K + k0 + kk;
      *(half8*)(&Ah[m * 72 + kk]) = *(const half8*)(Ahi + ra);
      *(half8*)(&Al[m * 72 + kk]) = *(const half8*)(Alo + ra);
      *(half8*)(&Bh[m * 72 + kk]) = *(const half8*)(Bhi + rb);
      *(half8*)(&Bl[m * 72 + kk]) = *(const half8*)(Blo + rb);
    }
    __syncthreads();
#pragma unroll
    for (int ks = 0; ks < 2; ++ks) {
      half8 ah[2], al[2], bh[4], bl[4];
#pragma unroll
      for (int mt = 0; mt < 2; ++mt) {
        int ro = (wm * 32 + mt * 16 + lc) * 72 + ks * 32 + (lg << 3);
        ah[mt] = *(half8*)(&Ah[ro]);
        al[mt] = *(half8*)(&Al[ro]);
      }
#pragma unroll
      for (int nf = 0; nf < 4; ++nf) {
        int ro = (wn * 64 + nf * 16 + lc) * 72 + ks * 32 + (lg << 3);
        bh[nf] = *(half8*)(&Bh[ro]);
        bl[nf] = *(half8*)(&Bl[ro]);
      }
#pragma unroll
      for (int mt = 0; mt < 2; ++mt)
#pragma unroll
        for (int nf = 0; nf < 4; ++nf) {
          accl[mt][nf] = mfma_fp16(al[mt], bh[nf], accl[mt][nf]);
          accl[mt][nf] = mfma_fp16(ah[mt], bl[nf], accl[mt][nf]);
          acch[mt][nf] = mfma_fp16(ah[mt], bh[nf], acch[mt][nf]);
        }
    }
  }

#pragma unroll
  for (int mt = 0; mt < 2; ++mt)
#pragma unroll
    for (int nf = 0; nf < 4; ++nf) {
      int col = n0 + wn * 64 + nf * 16 + lc;
      int row0 = m0 + wm * 32 + mt * 16 + (lg << 2);
      float bv = bias[col];
#pragma unroll
      for (int rr = 0; rr < 4; ++rr) {
        int row = row0 + rr;
        float v = acch[mt][nf][rr] + accl[mt][nf][rr] * (1.0f / 1024.0f) + bv;
        _Float16 h = (_Float16)v;
        _Float16 l = (_Float16)((v - (float)h) * 1024.0f);
        if (mode == 0) {
          Chi[(size_t)row * 768 + col] = h;
          Clo[(size_t)row * 768 + col] = l;
        } else {
          int b = row >> 13, pos = row & 8191;
          int hh = col >> 6, d = col & 63;
          int g = hh >> 2;
          int rdil = 1 << g;
          if ((pos & (rdil - 1)) == g) {
            int t = (pos - g) >> g;
            int Ng = 8192 >> g;
            Chi[vt_base(b, hh) + d * Ng + t] = h;
            Clo[vt_base(b, hh) + d * Ng + t] = l;
          }
        }
      }
    }
}

// Single fp16 GEMM for output projection: C(fp32) = A(fp32) @ Wt^T + bias
__global__ __launch_bounds__(256) void gemm1_kernel(
    const float* __restrict__ A, const _Float16* __restrict__ Bt,
    const float* __restrict__ bias, float* __restrict__ C) {
  const int K = 768, N = 768;
  __shared__ _Float16 As[128 * 72];
  __shared__ _Float16 Bs[128 * 72];
  int tid = threadIdx.x;
  int m0 = blockIdx.y * 128, n0 = blockIdx.x * 128;
  int lane = tid & 63, wid = tid >> 6;
  int wm = wid >> 1, wn = wid & 1;
  int lg = lane >> 4, lc = lane & 15;

  f32x4 acc[4][4] = {};

  for (int k0 = 0; k0 < K; k0 += 64) {
    __syncthreads();
#pragma unroll
    for (int c = 0; c < 4; ++c) {
      int idx = c * 256 + tid;
      int m = idx >> 3, kk = (idx & 7) << 3;
      const float* src = A + (size_t)(m0 + m) * K + k0 + kk;
      f32x4 x0 = *(const f32x4*)src;
      f32x4 x1 = *(const f32x4*)(src + 4);
      half8 v;
#pragma unroll
      for (int j = 0; j < 4; ++j) { v[j] = (_Float16)x0[j]; v[4 + j] = (_Float16)x1[j]; }
      *(half8*)(&As[m * 72 + kk]) = v;
      *(half8*)(&Bs[m * 72 + kk]) = *(const half8*)(Bt + (size_t)(n0 + m) * K + k0 + kk);
    }
    __syncthreads();
#pragma unroll
    for (int ks = 0; ks < 2; ++ks) {
      half8 af[4], bf[4];
#pragma unroll
      for (int mt = 0; mt < 4; ++mt)
        af[mt] = *(half8*)(&As[(wm * 64 + mt * 16 + lc) * 72 + ks * 32 + (lg << 3)]);
#pragma unroll
      for (int nf = 0; nf < 4; ++nf)
        bf[nf] = *(half8*)(&Bs[(wn * 64 + nf * 16 + lc) * 72 + ks * 32 + (lg << 3)]);
#pragma unroll
      for (int mt = 0; mt < 4; ++mt)
#pragma unroll
        for (int nf = 0; nf < 4; ++nf)
          acc[mt][nf] = mfma_fp16(af[mt], bf[nf], acc[mt][nf]);
    }
  }

#pragma unroll
  for (int mt = 0; mt < 4; ++mt)
#pragma unroll
    for (int nf = 0; nf < 4; ++nf) {
      int col = n0 + wn * 64 + nf * 16 + lc;
      int row0 = m0 + wm * 64 + mt * 16 + (lg << 2);
      float bv = bias[col];
#pragma unroll
      for (int rr = 0; rr < 4; ++rr)
        C[(size_t)(row0 + rr) * N + col] = acc[mt][nf][rr] + bv;
    }
}

// Two-pass dilated flash attention, fp16-pair precision.
// 512 threads (8 waves), 128 q-rows/block, XCD-swizzled, 52.2KB LDS.
// NOTE: 2nd launch_bounds arg behaves as BLOCKS/CU on this toolchain; 6 caused
// VGPR=40 + catastrophic scratch spills (R5). Keep 4 (VGPR=60, no spill).
__global__ __launch_bounds__(512, 4) void attn_kernel(
    const _Float16* __restrict__ Qh, const _Float16* __restrict__ Ql,
    const _Float16* __restrict__ Kh, const _Float16* __restrict__ Kl,
    const _Float16* __restrict__ Vth, const _Float16* __restrict__ Vtl,
    float* __restrict__ X, float* __restrict__ wbuf) {
  __shared__ _Float16 Ksh[64 * 64], Ksl[64 * 64];   // XOR-swizzled, stride 64
  __shared__ _Float16 Vsh[64 * 64], Vsl[64 * 64];
  __shared__ _Float16 Ps[8 * 16 * 68];              // P: stride 68 (conflict-free writes)
  __shared__ float colred[8][64];

  // XCD-aware decode: pin each unit's 16 q-blocks to one XCD (K/V L2 reuse).
  int bid = blockIdx.x;
  int xcd = bid & 7, idx = bid >> 3;          // 112 slots/XCD = 7 units x 16 qblk
  int u_glob = xcd * 7 + (idx >> 4);          // 0..55
  int qblk = idx & 15;
  int g = (u_glob < 32) ? 0 : (u_glob < 48) ? 1 : 2;
  int u = (g == 0) ? u_glob : (g == 1) ? u_glob - 32 : u_glob - 48;
  int nsegs = 4 >> g;
  int b = u / (nsegs * 4), rem = u % (nsegs * 4);
  int nseg = rem >> 2, hg = rem & 3;
  int head = g * 4 + hg;
  int s = 2048 << g, r = 1 << g, off = g;
  int Ng = 8192 >> g;
  int tbase = nseg * 2048;
  int vbase = vt_base(b, head);

  int tid = threadIdx.x, lane = tid & 63, wid = tid >> 6;
  int lg = lane >> 4, lc = lane & 15;

  int q0 = qblk * 128 + wid * 16;
  half8 qfh[2], qfl[2];
  {
    int q = q0 + lc;
    int pos = nseg * s + off + q * r;
    size_t ro = (size_t)(b * 8192 + pos) * 768 + head * 64;
#pragma unroll
    for (int ks = 0; ks < 2; ++ks) {
      qfh[ks] = *(const half8*)(Qh + ro + ks * 32 + (lg << 3));
      qfl[ks] = *(const half8*)(Ql + ro + ks * 32 + (lg << 3));
    }
  }

  // Hoisted staging addresses (stride over kt is constant).
  int kr = tid >> 3, kcb = (tid & 7) << 4;  // row, col-bytes (16B per thread)
  const int kc = (tid & 7) << 3;            // col elems
  size_t kro = (size_t)(b * 8192 + nseg * s + off + kr * r) * 768 + head * 64 + kc;
  size_t vro = (size_t)vbase + (size_t)kr * Ng + tbase + kc;
  const size_t kstep = (size_t)64 * r * 768;
  _Float16* KshW = &Ksh[kva(kr, kcb)];
  _Float16* KslW = &Ksl[kva(kr, kcb)];
  _Float16* VshW = &Vsh[kva(kr, kcb)];
  _Float16* VslW = &Vsl[kva(kr, kcb)];

  // ---------- pass 1: cheap row sums (hi-only scores) ----------
  float psum[4] = {};
  {
    size_t kro1 = kro;
    for (int kt = 0; kt < 32; ++kt) {
      __syncthreads();
      *(half8*)KshW = *(const half8*)(Kh + kro1);
      kro1 += kstep;
      __syncthreads();
      f32x4 sc[4] = {};
#pragma unroll
      for (int ks = 0; ks < 2; ++ks)
#pragma unroll
        for (int nf = 0; nf < 4; ++nf) {
          half8 bf = *(half8*)(&Ksh[kva(nf * 16 + lc, ks * 64 + (lg << 4))]);
          sc[nf] = mfma_fp16(qfh[ks], bf, sc[nf]);
        }
#pragma unroll
      for (int rr = 0; rr < 4; ++rr) {
        float acc = 0.f;
#pragma unroll
        for (int nf = 0; nf < 4; ++nf) acc += __expf(sc[nf][rr] * 0.125f);
        psum[rr] += acc;
      }
    }
  }
  float inv_l[4];
#pragma unroll
  for (int rr = 0; rr < 4; ++rr) {
    float v = psum[rr];
#pragma unroll
    for (int msk = 1; msk < 16; msk <<= 1) v += __shfl_xor(v, msk, 64);
    inv_l[rr] = 1.0f / v;
  }

  // ---------- pass 2: precise scores, PV, column sums ----------
  f32x4 acch[4] = {};
  f32x4 accl[4] = {};
  _Float16* Pw = Ps + wid * 16 * 68;
  int wrow = ((b * 12 + head) * 16 + qblk) * 8192 + tbase;

  for (int kt = 0; kt < 32; ++kt) {
    int kv0 = kt * 64;
    __syncthreads();
    // flush previous tile's column sums (colred complete as of the barrier)
    if (kt > 0 && tid < 64) {
      float w4 = 0.f;
#pragma unroll
      for (int w = 0; w < 8; ++w) w4 += colred[w][tid];
      wbuf[wrow + (kv0 - 64) + tid] = w4;
    }
    *(half8*)KshW = *(const half8*)(Kh + kro);
    *(half8*)KslW = *(const half8*)(Kl + kro);
    *(half8*)VshW = *(const half8*)(Vth + vro);
    *(half8*)VslW = *(const half8*)(Vtl + vro);
    kro += kstep;
    vro += 64;
    __syncthreads();

    // precise scores: s = hi*hi + (hi*lo + lo*hi)/1024
    f32x4 sc[4];
#pragma unroll
    for (int nf = 0; nf < 4; ++nf) {
      half8 kh[2], kl[2];
#pragma unroll
      for (int ks = 0; ks < 2; ++ks) {
        int ro = kva(nf * 16 + lc, ks * 64 + (lg << 4));
        kh[ks] = *(half8*)(&Ksh[ro]);
        kl[ks] = *(half8*)(&Ksl[ro]);
      }
      f32x4 t = {};
#pragma unroll
      for (int ks = 0; ks < 2; ++ks) {
        t = mfma_fp16(qfl[ks], kh[ks], t);
        t = mfma_fp16(qfh[ks], kl[ks], t);
      }
#pragma unroll
      for (int rr = 0; rr < 4; ++rr) t[rr] *= (1.0f / 1024.0f);
#pragma unroll
      for (int ks = 0; ks < 2; ++ks)
        t = mfma_fp16(qfh[ks], kh[ks], t);
      sc[nf] = t;
    }

    // p = e^{s/8} / l, rounded to fp16; column sums use the ROUNDED p
#pragma unroll
    for (int nf = 0; nf < 4; ++nf)
#pragma unroll
      for (int rr = 0; rr < 4; ++rr) {
        float p = __expf(sc[nf][rr] * 0.125f) * inv_l[rr];
        sc[nf][rr] = (float)(_Float16)p;
      }

#pragma unroll
    for (int nf = 0; nf < 4; ++nf) {
      float cs = sc[nf][0] + sc[nf][1] + sc[nf][2] + sc[nf][3];
      cs += __shfl_xor(cs, 16, 64);
      cs += __shfl_xor(cs, 32, 64);
      if (lane < 16) colred[wid][nf * 16 + lc] = cs;
    }

    // P -> per-wave LDS (D-layout -> A-layout), stride 68
#pragma unroll
    for (int nf = 0; nf < 4; ++nf)
#pragma unroll
      for (int rr = 0; rr < 4; ++rr)
        Pw[((lg << 2) + rr) * 68 + nf * 16 + lc] = (_Float16)sc[nf][rr];

    // PV: x = sum p*(vh + vl/1024)   (per-wave P buffer: no barrier needed)
#pragma unroll
    for (int ks2 = 0; ks2 < 2; ++ks2) {
      half4 plo = *(half4*)(&Pw[lc * 68 + ks2 * 32 + (lg << 3)]);
      half4 phi = *(half4*)(&Pw[lc * 68 + ks2 * 32 + (lg << 3) + 4]);
      half8 pa;
#pragma unroll
      for (int j = 0; j < 4; ++j) { pa[j] = plo[j]; pa[4 + j] = phi[j]; }
#pragma unroll
      for (int nf = 0; nf < 4; ++nf) {
        int ro = kva(nf * 16 + lc, ks2 * 64 + (lg << 4));
        half8 vh = *(half8*)(&Vsh[ro]);
        half8 vl = *(half8*)(&Vsl[ro]);
        acch[nf] = mfma_fp16(pa, vh, acch[nf]);
        accl[nf] = mfma_fp16(pa, vl, accl[nf]);
      }
    }
  }
  __syncthreads();
  if (tid < 64) {
    float w4 = 0.f;
#pragma unroll
    for (int w = 0; w < 8; ++w) w4 += colred[w][tid];
    wbuf[wrow + 31 * 64 + tid] = w4;
  }

  // epilogue
#pragma unroll
  for (int rr = 0; rr < 4; ++rr) {
    int q = q0 + (lg << 2) + rr;
    int pos = nseg * s + off + q * r;
    float* xr = X + (size_t)(b * 8192 + pos) * 768 + head * 64;
#pragma unroll
    for (int nf = 0; nf < 4; ++nf)
      xr[nf * 16 + lc] = acch[nf][rr] + accl[nf][rr] * (1.0f / 1024.0f);
  }
}

// wtot[b,h,t] = sum over 16 qblk partials
__global__ __launch_bounds__(256) void wreduce_kernel(const float* __restrict__ wbuf,
                                                      float* __restrict__ wtot) {
  int bh = blockIdx.y;
  int t = blockIdx.x * 256 + threadIdx.x;
  int h = bh % 12, g = h >> 2, Ng = 8192 >> g;
  if (t >= Ng) return;
  const float* src = wbuf + (size_t)bh * 16 * 8192 + t;
  float sacc = 0.f;
#pragma unroll
  for (int qb = 0; qb < 16; ++qb) sacc += src[qb * 8192];
  wtot[bh * 8192 + t] = sacc;
}

// div[b,h,d] = sum_t wtot[b,h,t] * (vh + vl/1024)  — consistent with PV's V
__global__ __launch_bounds__(256) void divgemm_kernel(const float* __restrict__ wtot,
                                                      const _Float16* __restrict__ Vth,
                                                      const _Float16* __restrict__ Vtl,
                                                      float* __restrict__ divbuf) {
  int bhd = blockIdx.x;  // 0..1535
  int b = bhd / 768, e = bhd % 768;
  int h = e >> 6, d = e & 63;
  int g = h >> 2, Ng = 8192 >> g;
  const _Float16* vph = Vth + vt_base(b, h) + d * Ng;
  const _Float16* vpl = Vtl + vt_base(b, h) + d * Ng;
  const float* wp = wtot + (b * 12 + h) * 8192;
  int tid = threadIdx.x;
  float sacc = 0.f;
  for (int t = tid; t < Ng; t += 256) {
    float v = (float)vph[t] + (float)vpl[t] * (1.0f / 1024.0f);
    sacc += wp[t] * v;
  }
  __shared__ float red[256];
  red[tid] = sacc;
  __syncthreads();
  for (int o = 128; o > 0; o >>= 1) {
    if (tid < o) red[tid] += red[tid + o];
    __syncthreads();
  }
  if (tid == 0) divbuf[b * 768 + e] = red[0];
}

// LayerNorm fusing the /(div*3) normalization + written-slot mask. In-place on X.
__global__ __launch_bounds__(256) void ln_kernel(float* __restrict__ X,
                                                 const float* __restrict__ divbuf,
                                                 const float* __restrict__ ln_w,
                                                 const float* __restrict__ ln_b) {
  int row = blockIdx.x;
  int b = row >> 13, pos = row & 8191;
  int tid = threadIdx.x;
  float x[3];
#pragma unroll
  for (int j = 0; j < 3; ++j) {
    int e = tid + 256 * j;
    int h = e >> 6, g = h >> 2;
    bool wr = (g == 0) || (g == 1 && (pos & 1) == 1) || (g == 2 && (pos & 3) == 2);
    float v = 0.f;
    if (wr) v = X[(size_t)row * 768 + e] / (divbuf[b * 768 + e] * 3.0f);
    x[j] = v;
  }
  float s1 = x[0] + x[1] + x[2];
  float s2 = x[0] * x[0] + x[1] * x[1] + x[2] * x[2];
  __shared__ float red[512];
  red[tid] = s1;
  red[256 + tid] = s2;
  __syncthreads();
  for (int o = 128; o > 0; o >>= 1) {
    if (tid < o) {
      red[tid] += red[tid + o];
      red[256 + tid] += red[256 + tid + o];
    }
    __syncthreads();
  }
  float mean = red[0] * (1.0f / 768.0f);
  float var = red[256] * (1.0f / 768.0f) - mean * mean;
  float inv = rsqrtf(var + 1e-5f);
#pragma unroll
  for (int j = 0; j < 3; ++j) {
    int e = tid + 256 * j;
    X[(size_t)row * 768 + e] = (x[j] - mean) * inv * ln_w[e] + ln_b[e];
  }
}

extern "C" void kernel_launch(void* const* d_in, const int* in_sizes, int n_in,
                              void* d_out, int out_size, void* d_ws, size_t ws_size,
                              hipStream_t stream) {
  const float* query = (const float*)d_in[0];
  const float* key   = (const float*)d_in[1];
  const float* value = (const float*)d_in[2];
  const float* Wq = (const float*)d_in[3];
  const float* bq = (const float*)d_in[4];
  const float* Wk = (const float*)d_in[5];
  const float* bk = (const float*)d_in[6];
  const float* Wv = (const float*)d_in[7];
  const float* bv = (const float*)d_in[8];
  const float* Wo = (const float*)d_in[9];
  const float* bo = (const float*)d_in[10];
  const float* ln_w = (const float*)d_in[11];
  const float* ln_b = (const float*)d_in[12];

  char* ws = (char*)d_ws;
  _Float16* Wsh = (_Float16*)ws; ws += (size_t)4 * 589824 * 2;   // 4 hi planes
  _Float16* Wsl = (_Float16*)ws; ws += (size_t)4 * 589824 * 2;   // 4 lo planes
  _Float16* Qhb = (_Float16*)ws; ws += (size_t)16384 * 768 * 2;
  _Float16* Qlb = (_Float16*)ws; ws += (size_t)16384 * 768 * 2;
  _Float16* Khb = (_Float16*)ws; ws += (size_t)16384 * 768 * 2;
  _Float16* Klb = (_Float16*)ws; ws += (size_t)16384 * 768 * 2;
  _Float16* Vth = (_Float16*)ws; ws += (size_t)7340032 * 2;
  _Float16* Vtl = (_Float16*)ws; ws += (size_t)7340032 * 2;
  float* Xbuf = (float*)ws; ws += (size_t)16384 * 768 * 4;
  float* wbuf = (float*)ws; ws += (size_t)24 * 16 * 8192 * 4;
  float* wtot = (float*)ws; ws += (size_t)24 * 8192 * 4;
  float* divbuf = (float*)ws; ws += 2 * 768 * 4;

  // A-plane scratch aliases Xbuf (exactly 16384*768*2B*2 = Xbuf bytes).
  // Safe: planes are dead before attn writes X; ln only reads attn-written slots.
  _Float16* Ahi = (_Float16*)Xbuf;
  _Float16* Alo = Ahi + (size_t)16384 * 768;

  wsplit4_kernel<<<dim3(2304, 4), 256, 0, stream>>>(Wq, Wk, Wv, Wo, Wsh, Wsl);

  dim3 ggrid(6, 128);
  asplit_kernel<<<6144, 256, 0, stream>>>(query, Ahi, Alo);
  gemm3_kernel<<<ggrid, 512, 0, stream>>>(Ahi, Alo, Wsh, Wsl, bq, Qhb, Qlb, 0);
  asplit_kernel<<<6144, 256, 0, stream>>>(key, Ahi, Alo);
  gemm3_kernel<<<ggrid, 512, 0, stream>>>(Ahi, Alo, Wsh + 589824, Wsl + 589824, bk, Khb, Klb, 0);
  asplit_kernel<<<6144, 256, 0, stream>>>(value, Ahi, Alo);
  gemm3_kernel<<<ggrid, 512, 0, stream>>>(Ahi, Alo, Wsh + 2 * 589824, Wsl + 2 * 589824, bv, Vth, Vtl, 1);

  attn_kernel<<<896, 512, 0, stream>>>(Qhb, Qlb, Khb, Klb, Vth, Vtl, Xbuf, wbuf);

  wreduce_kernel<<<dim3(32, 24), 256, 0, stream>>>(wbuf, wtot);
  divgemm_kernel<<<1536, 256, 0, stream>>>(wtot, Vth, Vtl, divbuf);
  ln_kernel<<<16384, 256, 0, stream>>>(Xbuf, divbuf, ln_w, ln_b);

  gemm1_kernel<<<ggrid, 256, 0, stream>>>(Xbuf, Wsh + 3 * 589824, bo, (float*)d_out);
}